// Round 2
// baseline (470.413 us; speedup 1.0000x reference)
//
#include <hip/hip_runtime.h>
#include <hip/hip_bf16.h>
#include <stdint.h>

#define HID    128
#define DT     0.1f
#define NITER  10
#define RT     64           // rows (b,q pairs) per tile
#define NT     256          // 4 waves
#define HSTR   136          // H row stride in bf16 elems (17 x 16B chunks, odd)
#define NTILES 4096         // (65536*4)/RT
#define PGRID  1024         // persistent: 4 blocks/CU * 256 CU
#define SCALE  2.885390081777927f   // 2*log2(e): folded into W1..3/b1..3

typedef __attribute__((ext_vector_type(8))) short bf16x8;   // MFMA A/B frag
typedef __attribute__((ext_vector_type(4))) float f32x4;    // MFMA C/D frag
typedef __attribute__((ext_vector_type(2))) unsigned int u32x2;

struct alignas(16) Smem {
    uint16_t hA[RT * HSTR];     // activations [batch][hid] bf16  (17408 B)
    uint16_t hB[RT * HSTR];     //                                (17408 B)
    uint16_t xb[RT * 8];        // X bf16 [row][8], cols 4..7 stay zero (1024 B)
    float    b1[HID], b2[HID], b3[HID];   // pre-scaled by SCALE  (1536 B)
    float    kk[RT * 4];        // K of current iter               (1024 B)
};  // total 38400 B -> 4 blocks/CU

__device__ __forceinline__ uint16_t f2bf(float f) {
    uint32_t u = __float_as_uint(f);
    return (uint16_t)((u + 0x7fffu + ((u >> 16) & 1u)) >> 16);
}

__device__ __forceinline__ uint32_t pk2(float a, float b) {
    __hip_bfloat162 h = __float22bfloat162_rn(float2{a, b});
    return *reinterpret_cast<uint32_t*>(&h);
}

// y = 2*log2(e)*x already (scale folded into weights/bias):
// tanh(x) = 1 - 2/(2^y + 1).  1 exp2 + 1 rcp + 1 add + 1 fma.
__device__ __forceinline__ float tanh_pre(float y) {
    float e = __builtin_amdgcn_exp2f(y);
    return fmaf(-2.0f, __builtin_amdgcn_rcpf(e + 1.0f), 1.0f);
}

// uniform scalar load -> SGPR
__device__ __forceinline__ float uread(const float* p) {
    return __uint_as_float(__builtin_amdgcn_readfirstlane(__float_as_uint(*p)));
}

// dst = tanh(src @ W + bias), transposed MFMA. Wave owns M-slice of 32
// (2 m-tiles), covers all 64 batch rows (4 n-tiles). bias/W pre-scaled.
__device__ __forceinline__ void dense_mfma(
    const bf16x8 (&wf)[2][4], const float* __restrict__ bias,
    const uint16_t* __restrict__ src, uint16_t* __restrict__ dst,
    int w, int ln, int g)
{
    f32x4 acc[2][4];
    #pragma unroll
    for (int mt = 0; mt < 2; ++mt) {
        f32x4 bs = *(const f32x4*)&bias[w * 32 + mt * 16 + 4 * g];
        #pragma unroll
        for (int nt = 0; nt < 4; ++nt) acc[mt][nt] = bs;
    }
    __builtin_amdgcn_s_setprio(1);
    #pragma unroll
    for (int kt = 0; kt < 4; ++kt) {
        bf16x8 bfr[4];
        #pragma unroll
        for (int nt = 0; nt < 4; ++nt)
            bfr[nt] = *(const bf16x8*)&src[(nt * 16 + ln) * HSTR + kt * 32 + 8 * g];
        #pragma unroll
        for (int mt = 0; mt < 2; ++mt)
            #pragma unroll
            for (int nt = 0; nt < 4; ++nt)
                acc[mt][nt] = __builtin_amdgcn_mfma_f32_16x16x32_bf16(wf[mt][kt], bfr[nt], acc[mt][nt], 0, 0, 0);
    }
    __builtin_amdgcn_s_setprio(0);
    #pragma unroll
    for (int mt = 0; mt < 2; ++mt) {
        int hb = w * 32 + mt * 16 + 4 * g;
        #pragma unroll
        for (int nt = 0; nt < 4; ++nt) {
            int r = nt * 16 + ln;
            u32x2 p;
            p.x = pk2(tanh_pre(acc[mt][nt][0]), tanh_pre(acc[mt][nt][1]));
            p.y = pk2(tanh_pre(acc[mt][nt][2]), tanh_pre(acc[mt][nt][3]));
            *(u32x2*)&dst[r * HSTR + hb] = p;
        }
    }
}

__global__ __launch_bounds__(NT, 4) void pinn_irk_mfma(
    const float* __restrict__ x0g,
    const float* __restrict__ w1g, const float* __restrict__ b1g,
    const float* __restrict__ w2g, const float* __restrict__ b2g,
    const float* __restrict__ w3g, const float* __restrict__ b3g,
    const float* __restrict__ w4g, const float* __restrict__ b4g,
    const float* __restrict__ l1g, const float* __restrict__ l2g,
    const float* __restrict__ l3g, const float* __restrict__ l4g,
    const float* __restrict__ alg, const float* __restrict__ beg,
    float* __restrict__ outg)
{
    __shared__ Smem S;
    const int t    = threadIdx.x;
    const int lane = t & 63;
    const int w    = t >> 6;        // wave 0..3: owns hid slice [w*32, w*32+32)
    const int ln   = lane & 15;
    const int g    = lane >> 4;     // quad
    const bool owner = (g == 0);
    const int r_own  = w * 16 + ln; // batch row owned by this lane (if owner)

    // ---- uniform params -> SGPRs (off the per-iter critical path) ----
    const float L0 = uread(l1g), L1v = uread(l2g), L2v = uread(l3g), L3v = uread(l4g);
    const float B40 = uread(b4g), B41 = uread(b4g + 1);
    const float B42 = uread(b4g + 2), B43 = uread(b4g + 3);
    const float BE0 = uread(beg), BE1 = uread(beg + 1);
    const float BE2 = uread(beg + 2), BE3 = uread(beg + 3);
    float A[16];
    #pragma unroll
    for (int i = 0; i < 16; ++i)
        A[i] = uread(alg + i);

    // ---- stage biases (pre-scaled) / zero xb pad ----
    if (t < HID) {
        S.b1[t] = b1g[t] * SCALE;
        S.b2[t] = b2g[t] * SCALE;
        S.b3[t] = b3g[t] * SCALE;
    }
    {   // zero cols 4..7 of xb (cols 0..3 written by owner lanes)
        int r = t >> 2, c = 4 + (t & 3);
        S.xb[r * 8 + c] = 0;
    }

    // ---- W4 A-frags: per-lane CONSTANTS -> registers (was LDS) ----
    // frag elem j (0..7) = W4[kt*32+8g+j][ln] for ln<4, else 0
    bf16x8 w4f[4];
    #pragma unroll
    for (int kt = 0; kt < 4; ++kt) {
        bf16x8 f;
        #pragma unroll
        for (int j = 0; j < 8; ++j) {
            int k = kt * 32 + 8 * g + j;
            f[j] = (ln < 4) ? (short)f2bf(w4g[k * 4 + ln]) : (short)0;
        }
        w4f[kt] = f;
    }

    // ---- weight fragments W1/W2/W3 (M-slice of 32 per wave), pre-scaled ----
    // A-frag of W^T: lane (ln,g), elem j -> W[k=kt*32+8g+j][m=w*32+mt*16+ln]
    bf16x8 w1f[2], w2f[2][4], w3f[2][4];
    {
        const int mcol = w * 32 + ln;
        #pragma unroll
        for (int mt = 0; mt < 2; ++mt) {
            bf16x8 f1;
            #pragma unroll
            for (int j = 0; j < 8; ++j) {
                int k = 8 * g + j;
                float v = (k < 4) ? w1g[k * HID + mcol + mt * 16] * SCALE : 0.0f;
                f1[j] = (short)f2bf(v);
            }
            w1f[mt] = f1;
            #pragma unroll
            for (int kt = 0; kt < 4; ++kt) {
                bf16x8 f2, f3;
                #pragma unroll
                for (int j = 0; j < 8; ++j) {
                    int k = kt * 32 + 8 * g + j;
                    f2[j] = (short)f2bf(w2g[k * HID + mcol + mt * 16] * SCALE);
                    f3[j] = (short)f2bf(w3g[k * HID + mcol + mt * 16] * SCALE);
                }
                w2f[mt][kt] = f2;
                w3f[mt][kt] = f3;
            }
        }
    }
    __syncthreads();

    // ==== persistent tile loop: exactly 4 tiles of 64 rows per block ====
    for (int tile = blockIdx.x; tile < NTILES; tile += PGRID) {

        // ---- owner-lane state: X0 / X in registers; init xb ----
        float X0r[4] = {0.f, 0.f, 0.f, 0.f};
        float Xr[4]  = {0.f, 0.f, 0.f, 0.f};
        if (owner) {
            const float* xp = x0g + (tile * (RT / 4) + (r_own >> 2)) * 4;
            #pragma unroll
            for (int c = 0; c < 4; ++c) { X0r[c] = xp[c]; Xr[c] = X0r[c]; }
            u32x2 p;
            p.x = pk2(Xr[0], Xr[1]);
            p.y = pk2(Xr[2], Xr[3]);
            *(u32x2*)&S.xb[r_own * 8] = p;
        }
        __syncthreads();

        #pragma unroll 1
        for (int it = 0; it < NITER; ++it) {
            // ---- L1: hA = tanh(X @ W1 + b1), K padded 4->32 ----
            {
                f32x4 acc[2][4];
                #pragma unroll
                for (int mt = 0; mt < 2; ++mt) {
                    f32x4 bs = *(const f32x4*)&S.b1[w * 32 + mt * 16 + 4 * g];
                    #pragma unroll
                    for (int nt = 0; nt < 4; ++nt) acc[mt][nt] = bs;
                }
                bf16x8 bfr[4];
                #pragma unroll
                for (int nt = 0; nt < 4; ++nt) bfr[nt] = (bf16x8){0,0,0,0,0,0,0,0};
                if (g == 0) {
                    #pragma unroll
                    for (int nt = 0; nt < 4; ++nt)
                        bfr[nt] = *(const bf16x8*)&S.xb[(nt * 16 + ln) * 8];
                }
                __builtin_amdgcn_s_setprio(1);
                #pragma unroll
                for (int mt = 0; mt < 2; ++mt)
                    #pragma unroll
                    for (int nt = 0; nt < 4; ++nt)
                        acc[mt][nt] = __builtin_amdgcn_mfma_f32_16x16x32_bf16(w1f[mt], bfr[nt], acc[mt][nt], 0, 0, 0);
                __builtin_amdgcn_s_setprio(0);
                #pragma unroll
                for (int mt = 0; mt < 2; ++mt) {
                    int hb = w * 32 + mt * 16 + 4 * g;
                    #pragma unroll
                    for (int nt = 0; nt < 4; ++nt) {
                        int r = nt * 16 + ln;
                        u32x2 p;
                        p.x = pk2(tanh_pre(acc[mt][nt][0]), tanh_pre(acc[mt][nt][1]));
                        p.y = pk2(tanh_pre(acc[mt][nt][2]), tanh_pre(acc[mt][nt][3]));
                        *(u32x2*)&S.hA[r * HSTR + hb] = p;
                    }
                }
            }
            __syncthreads();

            // ---- L2 ----
            dense_mfma(w2f, S.b2, S.hA, S.hB, w, ln, g);
            __syncthreads();

            // ---- L3 ----
            dense_mfma(w3f, S.b3, S.hB, S.hA, w, ln, g);
            __syncthreads();

            // ---- L4 + K update + X update (owner lanes) ----
            {
                f32x4 acc = (f32x4){0.f, 0.f, 0.f, 0.f};
                __builtin_amdgcn_s_setprio(1);
                #pragma unroll
                for (int kt = 0; kt < 4; ++kt) {
                    bf16x8 bfr = *(const bf16x8*)&S.hA[r_own * HSTR + kt * 32 + 8 * g];
                    acc = __builtin_amdgcn_mfma_f32_16x16x32_bf16(w4f[kt], bfr, acc, 0, 0, 0);
                }
                __builtin_amdgcn_s_setprio(0);
                if (owner) {
                    float h0 = acc[0] + B40, h1 = acc[1] + B41;
                    float h2 = acc[2] + B42, h3 = acc[3] + B43;
                    float kv0 = -L0 * h2 - L1v * Xr[2];
                    float kv1 = -L0 * h3 - L1v * Xr[3];
                    float kv2 =  L2v * h0 + L3v * Xr[0];
                    float kv3 =  L2v * h1 + L3v * Xr[1];
                    *(f32x4*)&S.kk[r_own * 4] = (f32x4){kv0, kv1, kv2, kv3};
                    #pragma unroll
                    for (int c = 0; c < 4; ++c) {
                        float s = kv0 * A[c] + kv1 * A[4 + c]
                                + kv2 * A[8 + c] + kv3 * A[12 + c];
                        Xr[c] = fmaf(DT, s, X0r[c]);
                    }
                    u32x2 p;
                    p.x = pk2(Xr[0], Xr[1]);
                    p.y = pk2(Xr[2], Xr[3]);
                    *(u32x2*)&S.xb[r_own * 8] = p;
                }
            }
            __syncthreads();
        }

        // ---- final combine: X1 = X0 + dt * sum_q beta_q K[:,q,:] ----
        // (kk read here; next tile's first write to kk is 4 barriers away -> safe)
        if (t < RT) {
            int bb = t >> 2, i = t & 3;
            float s = BE0 * S.kk[(bb * 4 + 0) * 4 + i]
                    + BE1 * S.kk[(bb * 4 + 1) * 4 + i]
                    + BE2 * S.kk[(bb * 4 + 2) * 4 + i]
                    + BE3 * S.kk[(bb * 4 + 3) * 4 + i];
            int bglob = tile * (RT / 4) + bb;
            outg[bglob * 4 + i] = x0g[bglob * 4 + i] + DT * s;
        }
        // no barrier needed: next tile's xb write doesn't touch kk, and the
        // tile-top __syncthreads orders xb for the next L1.
    }
}

extern "C" void kernel_launch(void* const* d_in, const int* in_sizes, int n_in,
                              void* d_out, int out_size, void* d_ws, size_t ws_size,
                              hipStream_t stream) {
    (void)in_sizes; (void)n_in; (void)d_ws; (void)ws_size; (void)out_size;

    dim3 grid(PGRID);                // persistent: 4 blocks/CU x 256 CU
    dim3 block(NT);

    pinn_irk_mfma<<<grid, block, 0, stream>>>(
        (const float*)d_in[0],
        (const float*)d_in[1],  (const float*)d_in[2],
        (const float*)d_in[3],  (const float*)d_in[4],
        (const float*)d_in[5],  (const float*)d_in[6],
        (const float*)d_in[7],  (const float*)d_in[8],
        (const float*)d_in[9],  (const float*)d_in[10],
        (const float*)d_in[11], (const float*)d_in[12],
        (const float*)d_in[13], (const float*)d_in[14],
        (float*)d_out);
}

// Round 3
// 405.630 us; speedup vs baseline: 1.1597x; 1.1597x over previous
//
#include <hip/hip_runtime.h>
#include <hip/hip_bf16.h>
#include <stdint.h>

#define HID    128
#define DT     0.1f
#define NITER  10
#define NTHR   512          // 8 waves per block
#define NW     8
#define RPW    32           // rows per wave-chunk (wave-private)
#define NBLK   256          // 1 block per CU
#define NCH    4            // chunks per wave: 256*8*4*32 = 262144 rows
#define SCALE  2.885390081777927f   // 2*log2(e) folded into W1..3/b1..3

typedef __attribute__((ext_vector_type(8))) short bf16x8;   // MFMA A/B frag
typedef __attribute__((ext_vector_type(4))) float f32x4;    // MFMA C/D frag
typedef __attribute__((ext_vector_type(2))) unsigned int u32x2;
typedef __attribute__((ext_vector_type(4))) unsigned int u32x4;

union FragU { bf16x8 v; uint32_t u[4]; };

// LDS: weights in MFMA-fragment order (shared, read-only after staging) +
// per-wave private activation buffers (NO cross-wave traffic -> no barriers).
struct alignas(16) Smem {
    uint32_t w2f[8 * 4 * 64 * 4];   // 32 KB  [(ot*4+kt)*64+lane][4 u32]
    uint32_t w3f[8 * 4 * 64 * 4];   // 32 KB
    uint32_t w1f[8 * 64 * 4];       //  8 KB  [ot*64+lane][4 u32] (K=4 padded)
    float    b1[HID], b2[HID], b3[HID];   // 1.5 KB, pre-scaled
    uint16_t hbuf[NW * RPW * HID];  // 64 KB  per-wave swizzled [row][feat]
};  // 137.5 KB -> 1 block/CU, 8 waves (2/SIMD), VGPR budget 256/wave

__device__ __forceinline__ uint16_t f2bf(float f) {
    uint32_t u = __float_as_uint(f);
    return (uint16_t)((u + 0x7fffu + ((u >> 16) & 1u)) >> 16);
}

__device__ __forceinline__ uint32_t pk2(float a, float b) {
    __hip_bfloat162 h = __float22bfloat162_rn(float2{a, b});
    return *reinterpret_cast<uint32_t*>(&h);
}

// y = 2*log2(e)*x already: tanh(x) = 1 - 2/(2^y + 1)
__device__ __forceinline__ float tanh_pre(float y) {
    float e = __builtin_amdgcn_exp2f(y);
    return fmaf(-2.0f, __builtin_amdgcn_rcpf(e + 1.0f), 1.0f);
}

__device__ __forceinline__ float uread(const float* p) {
    return __uint_as_float(__builtin_amdgcn_readfirstlane(__float_as_uint(*p)));
}

// h-buffer addressing: [row][feat] bf16, row stride 256 B, 16B-chunk XOR
// swizzle (chunk ^= row&7) -> uniform bank spread for both b64 writes and
// b128 reads (unswizzled would be 2x LDS-BW loss).
__device__ __forceinline__ void hstore(char* hb, int row, int ot, int g, const f32x4& a) {
    int off = row * 256 + ((32 * ot + 8 * g) ^ ((row & 7) << 4));
    u32x2 p;
    p.x = pk2(tanh_pre(a[0]), tanh_pre(a[1]));
    p.y = pk2(tanh_pre(a[2]), tanh_pre(a[3]));
    *(u32x2*)(hb + off) = p;
}

__device__ __forceinline__ bf16x8 hload(const char* hb, int row, int kt, int g) {
    int off = row * 256 + ((64 * kt + 16 * g) ^ ((row & 7) << 4));
    return *(const bf16x8*)(hb + off);
}

// One dense layer for this wave's 32 rows: h <- tanh(h @ W + b), in place.
// Reads all 8 h-frags into regs first (in-order per-wave DS makes the
// in-place overwrite safe), W-frags streamed from LDS (all waves read the
// same addresses -> broadcast-friendly).
__device__ __forceinline__ void dense_layer(
    char* hb, const uint32_t* __restrict__ wf, const float* __restrict__ bias,
    int ln, int g, int lane)
{
    bf16x8 hf[2][4];
    #pragma unroll
    for (int ct = 0; ct < 2; ++ct)
        #pragma unroll
        for (int kt = 0; kt < 4; ++kt)
            hf[ct][kt] = hload(hb, ct * 16 + ln, kt, g);
    #pragma unroll
    for (int ot = 0; ot < 8; ++ot) {
        f32x4 bs = *(const f32x4*)&bias[ot * 16 + 4 * g];
        f32x4 aA = bs, aB = bs;
        #pragma unroll
        for (int kt = 0; kt < 4; ++kt) {
            bf16x8 wfr = *(const bf16x8*)&wf[((ot * 4 + kt) * 64 + lane) * 4];
            aA = __builtin_amdgcn_mfma_f32_16x16x32_bf16(wfr, hf[0][kt], aA, 0, 0, 0);
            aB = __builtin_amdgcn_mfma_f32_16x16x32_bf16(wfr, hf[1][kt], aB, 0, 0, 0);
        }
        hstore(hb, ln, ot, g, aA);
        hstore(hb, 16 + ln, ot, g, aB);
    }
}

__global__ __launch_bounds__(NTHR, 2) void pinn_irk_rows(
    const float* __restrict__ x0g,
    const float* __restrict__ w1g, const float* __restrict__ b1g,
    const float* __restrict__ w2g, const float* __restrict__ b2g,
    const float* __restrict__ w3g, const float* __restrict__ b3g,
    const float* __restrict__ w4g, const float* __restrict__ b4g,
    const float* __restrict__ l1g, const float* __restrict__ l2g,
    const float* __restrict__ l3g, const float* __restrict__ l4g,
    const float* __restrict__ alg, const float* __restrict__ beg,
    float* __restrict__ outg)
{
    __shared__ Smem S;
    const int t    = threadIdx.x;
    const int blk  = blockIdx.x;
    const int lane = t & 63;
    const int w    = t >> 6;        // wave 0..7: owns its rows end-to-end
    const int ln   = lane & 15;
    const int g    = lane >> 4;
    const bool owner = (g == 0);    // lane ln owns rows base+ln and base+16+ln

    // ---- uniform params -> SGPRs ----
    const float L0 = uread(l1g), L1v = uread(l2g), L2v = uread(l3g), L3v = uread(l4g);
    const float B40 = uread(b4g), B41 = uread(b4g + 1);
    const float B42 = uread(b4g + 2), B43 = uread(b4g + 3);
    const float BE0 = uread(beg), BE1 = uread(beg + 1);
    const float BE2 = uread(beg + 2), BE3 = uread(beg + 3);
    float A[16];
    #pragma unroll
    for (int i = 0; i < 16; ++i) A[i] = uread(alg + i);

    // ---- stage W2/W3 fragments (pre-scaled): elem j of frag (ot,kt,lane)
    //      = W[k=kt*32+8*(lane>>4)+j][m=ot*16+(lane&15)] ----
    for (int s = t; s < 2048; s += NTHR) {
        int lane_s = s & 63, kto = s >> 6;
        int kt = kto & 3, ot = kto >> 2;
        int m = ot * 16 + (lane_s & 15), gs = lane_s >> 4;
        uint32_t f2[4], f3[4];
        #pragma unroll
        for (int jj = 0; jj < 4; ++jj) {
            int k = kt * 32 + 8 * gs + 2 * jj;
            f2[jj] = (uint32_t)f2bf(w2g[k * HID + m] * SCALE)
                   | ((uint32_t)f2bf(w2g[(k + 1) * HID + m] * SCALE) << 16);
            f3[jj] = (uint32_t)f2bf(w3g[k * HID + m] * SCALE)
                   | ((uint32_t)f2bf(w3g[(k + 1) * HID + m] * SCALE) << 16);
        }
        *(u32x4*)&S.w2f[s * 4] = (u32x4){f2[0], f2[1], f2[2], f2[3]};
        *(u32x4*)&S.w3f[s * 4] = (u32x4){f3[0], f3[1], f3[2], f3[3]};
    }
    // ---- stage W1 fragments (K=4 real, rest zero), one slot per thread ----
    {
        int lane_s = t & 63, ot = t >> 6;
        int gs = lane_s >> 4;
        uint32_t f[4] = {0u, 0u, 0u, 0u};
        if (gs == 0) {
            int m = ot * 16 + (lane_s & 15);
            f[0] = (uint32_t)f2bf(w1g[0 * HID + m] * SCALE)
                 | ((uint32_t)f2bf(w1g[1 * HID + m] * SCALE) << 16);
            f[1] = (uint32_t)f2bf(w1g[2 * HID + m] * SCALE)
                 | ((uint32_t)f2bf(w1g[3 * HID + m] * SCALE) << 16);
        }
        *(u32x4*)&S.w1f[t * 4] = (u32x4){f[0], f[1], f[2], f[3]};
    }
    if (t < HID) {
        S.b1[t] = b1g[t] * SCALE;
        S.b2[t] = b2g[t] * SCALE;
        S.b3[t] = b3g[t] * SCALE;
    }
    // ---- W4^T A-frags in registers (ocol=ln<4 real, else 0; unscaled) ----
    bf16x8 w4f[4];
    #pragma unroll
    for (int kt = 0; kt < 4; ++kt) {
        bf16x8 f;
        #pragma unroll
        for (int j = 0; j < 8; ++j) {
            int k = kt * 32 + 8 * g + j;
            f[j] = (ln < 4) ? (short)f2bf(w4g[k * 4 + ln]) : (short)0;
        }
        w4f[kt] = f;
    }
    __syncthreads();   // the ONLY block-wide barrier

    char* hb = (char*)&S.hbuf[w * RPW * HID];   // this wave's private 8 KB

    for (int ch = 0; ch < NCH; ++ch) {
        const int base = ((blk * NW + w) * NCH + ch) * RPW;
        // X0 of owner rows (all lanes load; only g==0 values matter)
        f32x4 XA0 = *(const f32x4*)&x0g[((base + ln) >> 2) * 4];
        f32x4 XB0 = *(const f32x4*)&x0g[((base + 16 + ln) >> 2) * 4];
        f32x4 XA = XA0, XB = XB0;
        f32x4 kvA = {0.f,0.f,0.f,0.f}, kvB = {0.f,0.f,0.f,0.f};

        #pragma unroll 1
        for (int it = 0; it < NITER; ++it) {
            // ---- X -> B-frags (k=0..3 real, rest zero; zeros on g>0) ----
            FragU xa, xb;
            xa.u[0] = owner ? pk2(XA[0], XA[1]) : 0u;
            xa.u[1] = owner ? pk2(XA[2], XA[3]) : 0u;
            xa.u[2] = 0u; xa.u[3] = 0u;
            xb.u[0] = owner ? pk2(XB[0], XB[1]) : 0u;
            xb.u[1] = owner ? pk2(XB[2], XB[3]) : 0u;
            xb.u[2] = 0u; xb.u[3] = 0u;

            // ---- L1: h = tanh(X @ W1 + b1) ----
            #pragma unroll
            for (int ot = 0; ot < 8; ++ot) {
                f32x4 bs = *(const f32x4*)&S.b1[ot * 16 + 4 * g];
                bf16x8 wfr = *(const bf16x8*)&S.w1f[(ot * 64 + lane) * 4];
                f32x4 aA = __builtin_amdgcn_mfma_f32_16x16x32_bf16(wfr, xa.v, bs, 0, 0, 0);
                f32x4 aB = __builtin_amdgcn_mfma_f32_16x16x32_bf16(wfr, xb.v, bs, 0, 0, 0);
                hstore(hb, ln, ot, g, aA);
                hstore(hb, 16 + ln, ot, g, aB);
            }
            // ---- L2, L3 ----
            dense_layer(hb, S.w2f, S.b2, ln, g, lane);
            dense_layer(hb, S.w3f, S.b3, ln, g, lane);

            // ---- L4 + K + X update ----
            {
                bf16x8 hf[2][4];
                #pragma unroll
                for (int ct = 0; ct < 2; ++ct)
                    #pragma unroll
                    for (int kt = 0; kt < 4; ++kt)
                        hf[ct][kt] = hload(hb, ct * 16 + ln, kt, g);
                f32x4 kA = {0.f,0.f,0.f,0.f}, kB = {0.f,0.f,0.f,0.f};
                #pragma unroll
                for (int kt = 0; kt < 4; ++kt) {
                    kA = __builtin_amdgcn_mfma_f32_16x16x32_bf16(w4f[kt], hf[0][kt], kA, 0, 0, 0);
                    kB = __builtin_amdgcn_mfma_f32_16x16x32_bf16(w4f[kt], hf[1][kt], kB, 0, 0, 0);
                }
                // owner lanes (g==0) hold K[row][0..3] in kA/kB regs
                float h0 = kA[0] + B40, h1 = kA[1] + B41;
                float h2 = kA[2] + B42, h3 = kA[3] + B43;
                kvA = (f32x4){-L0 * h2 - L1v * XA[2], -L0 * h3 - L1v * XA[3],
                               L2v * h0 + L3v * XA[0],  L2v * h1 + L3v * XA[1]};
                h0 = kB[0] + B40; h1 = kB[1] + B41;
                h2 = kB[2] + B42; h3 = kB[3] + B43;
                kvB = (f32x4){-L0 * h2 - L1v * XB[2], -L0 * h3 - L1v * XB[3],
                               L2v * h0 + L3v * XB[0],  L2v * h1 + L3v * XB[1]};
                #pragma unroll
                for (int c = 0; c < 4; ++c) {
                    float sA = kvA[0] * A[c] + kvA[1] * A[4 + c]
                             + kvA[2] * A[8 + c] + kvA[3] * A[12 + c];
                    float sB = kvB[0] * A[c] + kvB[1] * A[4 + c]
                             + kvB[2] * A[8 + c] + kvB[3] * A[12 + c];
                    XA[c] = fmaf(DT, sA, XA0[c]);
                    XB[c] = fmaf(DT, sB, XB0[c]);
                }
            }
        }

        // ---- final combine (wave-local via private LDS scratch) ----
        if (owner) {
            *(f32x4*)(hb + ln * 16)        = kvA;
            *(f32x4*)(hb + (16 + ln) * 16) = kvB;
        }
        // in-order per-wave DS + compiler lgkmcnt make the reads safe
        if (lane < 32) {
            const float* kk = (const float*)hb;
            int bl_ = lane >> 2, i = lane & 3;
            float s = BE0 * kk[(bl_ * 4 + 0) * 4 + i]
                    + BE1 * kk[(bl_ * 4 + 1) * 4 + i]
                    + BE2 * kk[(bl_ * 4 + 2) * 4 + i]
                    + BE3 * kk[(bl_ * 4 + 3) * 4 + i];
            int idx = base + lane;   // = (base/4 + bl_)*4 + i
            outg[idx] = x0g[idx] + DT * s;
        }
    }
}

extern "C" void kernel_launch(void* const* d_in, const int* in_sizes, int n_in,
                              void* d_out, int out_size, void* d_ws, size_t ws_size,
                              hipStream_t stream) {
    (void)in_sizes; (void)n_in; (void)d_ws; (void)ws_size; (void)out_size;

    dim3 grid(NBLK);    // 1 block per CU, 8 waves each, barrier-free main loop
    dim3 block(NTHR);

    pinn_irk_rows<<<grid, block, 0, stream>>>(
        (const float*)d_in[0],
        (const float*)d_in[1],  (const float*)d_in[2],
        (const float*)d_in[3],  (const float*)d_in[4],
        (const float*)d_in[5],  (const float*)d_in[6],
        (const float*)d_in[7],  (const float*)d_in[8],
        (const float*)d_in[9],  (const float*)d_in[10],
        (const float*)d_in[11], (const float*)d_in[12],
        (const float*)d_in[13], (const float*)d_in[14],
        (float*)d_out);
}